// Round 12
// baseline (571.963 us; speedup 1.0000x reference)
//
#include <hip/hip_runtime.h>
#include <cstdint>
#include <cstddef>

#define B_  64
#define O_  36
#define D_  512
#define P_  (O_*O_)     // 1296 pairs per batch
#define BO_ (B_*O_)     // 2304 object rows

typedef short s8v __attribute__((ext_vector_type(8)));   // 8 bf16 (4 VGPRs)
typedef float f4v __attribute__((ext_vector_type(4)));   // MFMA accumulator

// RNE float->bf16 split: x ~= hi + lo with ~16 mantissa bits total.
__device__ __forceinline__ void bsplit(float x, short& hi, short& lo) {
    unsigned u = __float_as_uint(x);
    unsigned r = (u + 0x7FFFu + ((u >> 16) & 1u)) >> 16;
    hi = (short)r;
    float hf = __uint_as_float(r << 16);
    float d = x - hf;
    unsigned u2 = __float_as_uint(d);
    unsigned r2 = (u2 + 0x7FFFu + ((u2 >> 16) & 1u)) >> 16;
    lo = (short)r2;
}

// ---------------------------------------------------------------------------
// Kernel 0: split W2 ([512][512]) and repack+split W1 ([512][1024]->[1024][512])
// into bf16 hi/lo; also zeroes the s accumulator (replaces memset launch).
// ---------------------------------------------------------------------------
__global__ __launch_bounds__(256) void wsplit_all(
    const float* __restrict__ W2, const float* __restrict__ W1,
    short* __restrict__ W2h, short* __restrict__ W2l,
    short* __restrict__ W1h, short* __restrict__ W1l,
    float* __restrict__ s)
{
    const int gt = blockIdx.x * 256 + threadIdx.x;
    if (gt < 8192)   // zero s: 8192 * float4 = 64*512 floats
        *(float4*)&s[gt * 4] = make_float4(0.f, 0.f, 0.f, 0.f);
    int i = gt * 4;
    float4 w;
    short* hip_; short* lop_; int o;
    if (i < 512 * 512) {
        w = *(const float4*)&W2[i];
        hip_ = W2h; lop_ = W2l; o = i;
    } else {
        o = i - 512 * 512;
        const int n = o >> 9, d = o & 511;
        w = *(const float4*)&W1[(size_t)(n & 511) * 1024 + ((n >> 9) << 9) + d];
        hip_ = W1h; lop_ = W1l;
    }
    short h0, l0, h1, l1, h2, l2, h3, l3;
    bsplit(w.x, h0, l0); bsplit(w.y, h1, l1);
    bsplit(w.z, h2, l2); bsplit(w.w, h3, l3);
    *(short4*)&hip_[o] = make_short4(h0, h1, h2, h3);
    *(short4*)&lop_[o] = make_short4(l0, l1, l2, l3);
}

// ---------------------------------------------------------------------------
// Kernel 1: U/V GEMM via split-bf16 MFMA (validated rounds 3/5/8, unchanged).
// ---------------------------------------------------------------------------
__global__ __launch_bounds__(256, 2) void uv_mfma(
    const float* __restrict__ objs,
    const short* __restrict__ W1h, const short* __restrict__ W1l,
    float* __restrict__ U, float* __restrict__ V)
{
    __shared__ short Ah[128 * 40];
    __shared__ short Al[128 * 40];
    __shared__ short Bh[128 * 40];
    __shared__ short Bl[128 * 40];

    const int tid  = threadIdx.x;
    const int lane = tid & 63;
    const int wid  = tid >> 6;
    const int wr   = wid >> 1, wc = wid & 1;
    const int rowbase = blockIdx.y * 128;   // 18 tiles over 2304
    const int colbase = blockIdx.x * 128;   // 8 tiles over 1024

    const int srow = tid >> 1;
    const int skq  = (tid & 1) * 8;
    const float* Xrow  = objs + (size_t)(rowbase + srow) * 512;
    const short* Whrow = W1h + (size_t)(colbase + srow) * 512;
    const short* Wlrow = W1l + (size_t)(colbase + srow) * 512;

    const int fr = lane & 15;
    const int sl = (lane >> 4) * 8;
    const int abase = (wr * 64 + fr) * 40 + sl;
    const int bbase = (wc * 64 + fr) * 40 + sl;

    f4v acc[4][4];
    const f4v zero = {0.f, 0.f, 0.f, 0.f};
    #pragma unroll
    for (int i = 0; i < 4; ++i)
        #pragma unroll
        for (int j = 0; j < 4; ++j) acc[i][j] = zero;

    for (int kt = 0; kt < 512; kt += 32) {
        __syncthreads();
        #pragma unroll
        for (int pass = 0; pass < 2; ++pass) {
            const int kq = skq + pass * 16;   // 0/8/16/24
            const float4 x0 = *(const float4*)&Xrow[kt + kq];
            const float4 x1 = *(const float4*)&Xrow[kt + kq + 4];
            float hx[8] = {x0.x, x0.y, x0.z, x0.w, x1.x, x1.y, x1.z, x1.w};
            s8v hi8, lo8;
            #pragma unroll
            for (int j = 0; j < 8; ++j) { short h, l; bsplit(hx[j], h, l); hi8[j] = h; lo8[j] = l; }
            *(s8v*)&Ah[srow * 40 + kq] = hi8;
            *(s8v*)&Al[srow * 40 + kq] = lo8;
            *(s8v*)&Bh[srow * 40 + kq] = *(const s8v*)&Whrow[kt + kq];
            *(s8v*)&Bl[srow * 40 + kq] = *(const s8v*)&Wlrow[kt + kq];
        }
        __syncthreads();

        s8v ah[4], al[4], bh[4], bl[4];
        #pragma unroll
        for (int f = 0; f < 4; ++f) {
            ah[f] = *(const s8v*)&Ah[abase + f * 640];
            al[f] = *(const s8v*)&Al[abase + f * 640];
            bh[f] = *(const s8v*)&Bh[bbase + f * 640];
            bl[f] = *(const s8v*)&Bl[bbase + f * 640];
        }
        #pragma unroll
        for (int fm = 0; fm < 4; ++fm)
            #pragma unroll
            for (int fn = 0; fn < 4; ++fn)
                acc[fm][fn] = __builtin_amdgcn_mfma_f32_16x16x32_bf16(ah[fm], bh[fn], acc[fm][fn], 0, 0, 0);
        #pragma unroll
        for (int fm = 0; fm < 4; ++fm)
            #pragma unroll
            for (int fn = 0; fn < 4; ++fn)
                acc[fm][fn] = __builtin_amdgcn_mfma_f32_16x16x32_bf16(ah[fm], bl[fn], acc[fm][fn], 0, 0, 0);
        #pragma unroll
        for (int fm = 0; fm < 4; ++fm)
            #pragma unroll
            for (int fn = 0; fn < 4; ++fn)
                acc[fm][fn] = __builtin_amdgcn_mfma_f32_16x16x32_bf16(al[fm], bh[fn], acc[fm][fn], 0, 0, 0);
    }

    float* dst = (colbase < 512) ? U : V;
    const int cb = colbase & 511;
    const int r4 = (lane >> 4) * 4;
    #pragma unroll
    for (int fm = 0; fm < 4; ++fm) {
        #pragma unroll
        for (int r = 0; r < 4; ++r) {
            const int row = rowbase + wr * 64 + fm * 16 + r4 + r;
            float* drow = &dst[(size_t)row * 512 + cb + wc * 64 + fr];
            #pragma unroll
            for (int fn = 0; fn < 4; ++fn) drow[fn * 16] = acc[fm][fn][r];
        }
    }
}

// ---------------------------------------------------------------------------
// Kernel 2: pair GEMM, pipelined. 128x128 tile, 4 waves, SINGLE barrier/iter.
// A (=h, built in VALU) double-buffered in LDS [2][4][128][8] (conflict-free,
// validated r8: 0 conflicts). B fragments read DIRECTLY global->reg (L2-hot
// pre-split W2), double-buffered regs, prefetched one iter ahead. Loop
// unrolled x2 so all buffer/reg-set indices are compile-time.
// LDS 34 KB; launch_bounds(256,2).
// ---------------------------------------------------------------------------
__global__ __launch_bounds__(256, 2) void pair_gemm(
    const float* __restrict__ U, const float* __restrict__ V,
    const float* __restrict__ b1,
    const short* __restrict__ W2h, const short* __restrict__ W2l,
    const float* __restrict__ b2,
    float* __restrict__ xout, float* __restrict__ s)
{
    __shared__ short Ah[2][4][128][8];   // [buf][k-octet][pair row][8 k]
    __shared__ short Al[2][4][128][8];
    __shared__ float b1s[512];

    const int tid  = threadIdx.x;
    const int lane = tid & 63;
    const int wid  = tid >> 6;          // 0..3
    const int wr   = wid >> 1, wc = wid & 1;
    const int b       = blockIdx.z;
    const int pbase   = blockIdx.y * 128;    // 11 tiles over 1296
    const int colbase = blockIdx.x * 128;    // 4 tiles over 512

    for (int g = tid; g < 512; g += 256) b1s[g] = b1[g];

    // A staging: thread covers row (tid&127), octets {a0, a0+1}
    const int arow = tid & 127;
    const int a0   = (tid >> 7) * 2;         // 0 or 2
    const int p    = pbase + arow;
    const bool valid = (p < P_);
    int ki = 0, mi = 0;
    if (valid) { ki = p / O_; mi = p - ki * O_; }
    const float* Urow = U + (size_t)(b * O_ + mi) * 512;
    const float* Vrow = V + (size_t)(b * O_ + ki) * 512;

    const int fr = lane & 15;           // frag row (A) / col (B)
    const int q  = lane >> 4;           // k-octet 0..3

    // B fragment pointers (direct global)
    const short* Bhp[4]; const short* Blp[4];
    #pragma unroll
    for (int f = 0; f < 4; ++f) {
        const size_t off = (size_t)(colbase + wc * 64 + f * 16 + fr) * 512 + q * 8;
        Bhp[f] = W2h + off; Blp[f] = W2l + off;
    }

    // raw A regs (one K-step ahead of the LDS buffer being built)
    float4 au0[2], au1[2], av0[2], av1[2];
    // B frag regs, two sets (double-buffered)
    s8v bhA[4], blA[4], bhB[4], blB[4];
    s8v ah[4], al[4];

#define LOAD_A(ktv) do { if (valid) { const int _k = (ktv); \
    _Pragma("unroll") for (int _j = 0; _j < 2; ++_j) { \
        const int _o = _k + (a0 + _j) * 8; \
        au0[_j] = *(const float4*)&Urow[_o]; au1[_j] = *(const float4*)&Urow[_o + 4]; \
        av0[_j] = *(const float4*)&Vrow[_o]; av1[_j] = *(const float4*)&Vrow[_o + 4]; } } } while (0)

#define BUILD_WRITE(bufi, ktv) do { const int _k = (ktv); \
    _Pragma("unroll") for (int _j = 0; _j < 2; ++_j) { \
        const int _oct = a0 + _j; \
        s8v _hi, _lo; \
        if (valid) { \
            const float4 _c0 = *(const float4*)&b1s[_k + _oct * 8]; \
            const float4 _c1 = *(const float4*)&b1s[_k + _oct * 8 + 4]; \
            float _hx[8]; \
            _hx[0] = fmaxf(au0[_j].x + av0[_j].x + _c0.x, 0.f); \
            _hx[1] = fmaxf(au0[_j].y + av0[_j].y + _c0.y, 0.f); \
            _hx[2] = fmaxf(au0[_j].z + av0[_j].z + _c0.z, 0.f); \
            _hx[3] = fmaxf(au0[_j].w + av0[_j].w + _c0.w, 0.f); \
            _hx[4] = fmaxf(au1[_j].x + av1[_j].x + _c1.x, 0.f); \
            _hx[5] = fmaxf(au1[_j].y + av1[_j].y + _c1.y, 0.f); \
            _hx[6] = fmaxf(au1[_j].z + av1[_j].z + _c1.z, 0.f); \
            _hx[7] = fmaxf(au1[_j].w + av1[_j].w + _c1.w, 0.f); \
            _Pragma("unroll") for (int _e = 0; _e < 8; ++_e) { short _h, _l; bsplit(_hx[_e], _h, _l); _hi[_e] = _h; _lo[_e] = _l; } \
        } else { \
            _Pragma("unroll") for (int _e = 0; _e < 8; ++_e) { _hi[_e] = 0; _lo[_e] = 0; } \
        } \
        *(s8v*)&Ah[bufi][_oct][arow][0] = _hi; \
        *(s8v*)&Al[bufi][_oct][arow][0] = _lo; } } while (0)

#define LOAD_B(ktv, BH, BL) do { const int _k = (ktv); \
    _Pragma("unroll") for (int _f = 0; _f < 4; ++_f) { \
        BH[_f] = *(const s8v*)&Bhp[_f][_k]; BL[_f] = *(const s8v*)&Blp[_f][_k]; } } while (0)

#define READ_FRAGS(bufi) do { \
    _Pragma("unroll") for (int _f = 0; _f < 4; ++_f) { \
        ah[_f] = *(const s8v*)&Ah[bufi][q][wr * 64 + _f * 16 + fr][0]; \
        al[_f] = *(const s8v*)&Al[bufi][q][wr * 64 + _f * 16 + fr][0]; } } while (0)

// product-major; per-accumulator order hh -> hl -> lh (numerics fixed, = r3/r8)
#define MFMA_STEP(BH, BL) do { \
    _Pragma("unroll") for (int _fm = 0; _fm < 4; ++_fm) \
        _Pragma("unroll") for (int _fn = 0; _fn < 4; ++_fn) \
            acc[_fm][_fn] = __builtin_amdgcn_mfma_f32_16x16x32_bf16(ah[_fm], BH[_fn], acc[_fm][_fn], 0, 0, 0); \
    _Pragma("unroll") for (int _fm = 0; _fm < 4; ++_fm) \
        _Pragma("unroll") for (int _fn = 0; _fn < 4; ++_fn) \
            acc[_fm][_fn] = __builtin_amdgcn_mfma_f32_16x16x32_bf16(ah[_fm], BL[_fn], acc[_fm][_fn], 0, 0, 0); \
    _Pragma("unroll") for (int _fm = 0; _fm < 4; ++_fm) \
        _Pragma("unroll") for (int _fn = 0; _fn < 4; ++_fn) \
            acc[_fm][_fn] = __builtin_amdgcn_mfma_f32_16x16x32_bf16(al[_fm], BH[_fn], acc[_fm][_fn], 0, 0, 0); \
    } while (0)

    f4v acc[4][4];
    const f4v zero = {0.f, 0.f, 0.f, 0.f};
    #pragma unroll
    for (int i = 0; i < 4; ++i)
        #pragma unroll
        for (int j = 0; j < 4; ++j) acc[i][j] = zero;

    // prologue: tile 0 into buf0; raw A for tile 1; B regs for tile 0
    LOAD_A(0);
    __syncthreads();            // b1s ready
    BUILD_WRITE(0, 0);
    LOAD_A(32);
    LOAD_B(0, bhA, blA);

    for (int it = 0; it < 8; ++it) {
        const int kt0 = it * 64;
        // ---- even step t=2*it: reads buf0, B regs set A
        __syncthreads();
        READ_FRAGS(0);
        LOAD_B(kt0 + 32, bhB, blB);                    // for t+1
        MFMA_STEP(bhA, blA);
        BUILD_WRITE(1, kt0 + 32);                      // tile t+1 -> buf1
        LOAD_A(kt0 + 64 > 480 ? 480 : kt0 + 64);       // raw for t+2
        // ---- odd step t=2*it+1: reads buf1, B regs set B
        __syncthreads();
        READ_FRAGS(1);
        LOAD_B(kt0 + 64 > 480 ? 480 : kt0 + 64, bhA, blA);  // for t+2
        MFMA_STEP(bhB, blB);
        if (it < 7) {
            BUILD_WRITE(0, kt0 + 64);                  // tile t+2 -> buf0
            LOAD_A(kt0 + 96 > 480 ? 480 : kt0 + 96);
        }
    }

    // ---- epilogue: bias+relu, store x_pairs, column sums (validated r3/r8)
    float b2v[4];
    #pragma unroll
    for (int fn = 0; fn < 4; ++fn) b2v[fn] = b2[colbase + wc * 64 + fn * 16 + fr];
    const int r4 = (lane >> 4) * 4;
    float csum[4] = {0.f, 0.f, 0.f, 0.f};
    #pragma unroll
    for (int fm = 0; fm < 4; ++fm) {
        const int prow0 = pbase + wr * 64 + fm * 16 + r4;
        #pragma unroll
        for (int r = 0; r < 4; ++r) {
            const int pp = prow0 + r;
            if (pp < P_) {
                float* xrow = &xout[(size_t)(b * P_ + pp) * 512 + colbase + wc * 64 + fr];
                #pragma unroll
                for (int fn = 0; fn < 4; ++fn) {
                    float x = fmaxf(acc[fm][fn][r] + b2v[fn], 0.f);
                    xrow[fn * 16] = x;
                    csum[fn] += x;
                }
            }
        }
    }
    #pragma unroll
    for (int fn = 0; fn < 4; ++fn) {
        csum[fn] += __shfl_xor(csum[fn], 16);
        csum[fn] += __shfl_xor(csum[fn], 32);
    }
    if (lane < 16) {
        #pragma unroll
        for (int fn = 0; fn < 4; ++fn)
            atomicAdd(&s[b * 512 + colbase + wc * 64 + fn * 16 + lane], csum[fn]);
    }
#undef LOAD_A
#undef BUILD_WRITE
#undef LOAD_B
#undef READ_FRAGS
#undef MFMA_STEP
}

// ---------------------------------------------------------------------------
// Kernel 3: BatchNorm over batch axis (batch stats, biased var). Unrolled for
// memory-level parallelism (64 independent strided loads per pass).
// ---------------------------------------------------------------------------
__global__ __launch_bounds__(512) void bn_kernel(
    const float* __restrict__ s, const float* __restrict__ gamma,
    const float* __restrict__ beta, float* __restrict__ sn)
{
    const int g = threadIdx.x;
    float v[64];
    #pragma unroll
    for (int b = 0; b < 64; ++b) v[b] = s[b * 512 + g];
    float mean = 0.f;
    #pragma unroll
    for (int b = 0; b < 64; ++b) mean += v[b];
    mean *= (1.f / B_);
    float var = 0.f;
    #pragma unroll
    for (int b = 0; b < 64; ++b) { const float d = v[b] - mean; var = fmaf(d, d, var); }
    var *= (1.f / B_);
    const float inv = 1.f / sqrtf(var + 1e-5f);
    const float ga = gamma[g], be = beta[g];
    #pragma unroll
    for (int b = 0; b < 64; ++b)
        sn[b * 512 + g] = (v[b] - mean) * inv * ga + be;
}

// ---------------------------------------------------------------------------
// Kernel 4: fused 2-layer MLP. One block per batch row, 512 threads.
//   a = relu(sn@W3^T + b3) in LDS; out = relu(a@W4^T + b4).
// ---------------------------------------------------------------------------
__global__ __launch_bounds__(512) void mlp_fused(
    const float* __restrict__ sn,
    const float* __restrict__ W3, const float* __restrict__ b3,
    const float* __restrict__ W4, const float* __restrict__ b4,
    float* __restrict__ out)
{
    __shared__ float xs[512];
    __shared__ float as_[512];
    const int b = blockIdx.x;
    const int f = threadIdx.x;
    xs[f] = sn[b * 512 + f];
    __syncthreads();
    float sum = 0.f;
    #pragma unroll 8
    for (int k = 0; k < 512; k += 4) {
        const float4 w4 = *(const float4*)&W3[(size_t)f * 512 + k];
        const float4 x4 = *(const float4*)&xs[k];
        sum = fmaf(w4.x, x4.x, sum); sum = fmaf(w4.y, x4.y, sum);
        sum = fmaf(w4.z, x4.z, sum); sum = fmaf(w4.w, x4.w, sum);
    }
    as_[f] = fmaxf(sum + b3[f], 0.f);
    __syncthreads();
    float sum2 = 0.f;
    #pragma unroll 8
    for (int k = 0; k < 512; k += 4) {
        const float4 w4 = *(const float4*)&W4[(size_t)f * 512 + k];
        const float4 x4 = *(const float4*)&as_[k];
        sum2 = fmaf(w4.x, x4.x, sum2); sum2 = fmaf(w4.y, x4.y, sum2);
        sum2 = fmaf(w4.z, x4.z, sum2); sum2 = fmaf(w4.w, x4.w, sum2);
    }
    out[b * 512 + f] = fmaxf(sum2 + b4[f], 0.f);
}

// ---------------------------------------------------------------------------
extern "C" void kernel_launch(void* const* d_in, const int* in_sizes, int n_in,
                              void* d_out, int out_size, void* d_ws, size_t ws_size,
                              hipStream_t stream)
{
    const float* objs  = (const float*)d_in[0];
    const float* W1    = (const float*)d_in[1];
    const float* b1    = (const float*)d_in[2];
    const float* W2    = (const float*)d_in[3];
    const float* b2    = (const float*)d_in[4];
    const float* gamma = (const float*)d_in[5];
    const float* beta  = (const float*)d_in[6];
    const float* W3    = (const float*)d_in[7];
    const float* b3    = (const float*)d_in[8];
    const float* W4    = (const float*)d_in[9];
    const float* b4    = (const float*)d_in[10];

    float* out  = (float*)d_out;           // agg: [64][512] first
    float* xout = out + B_ * 512;          // x_pairs: [64][1296][512]

    // workspace (floats then bf16): U, V, s, sn, W2h/l, W1h/l (~13 MB)
    float* U  = (float*)d_ws;
    float* V  = U  + (size_t)BO_ * 512;
    float* s  = V  + (size_t)BO_ * 512;
    float* sn = s  + B_ * 512;
    short* W2h = (short*)(sn + B_ * 512);
    short* W2l = W2h + (size_t)512 * 512;
    short* W1h = W2l + (size_t)512 * 512;
    short* W1l = W1h + (size_t)1024 * 512;

    wsplit_all<<<768, 256, 0, stream>>>(W2, W1, W2h, W2l, W1h, W1l, s);
    uv_mfma<<<dim3(8, 18), 256, 0, stream>>>(objs, W1h, W1l, U, V);
    pair_gemm<<<dim3(4, 11, B_), 256, 0, stream>>>(U, V, b1, W2h, W2l, b2, xout, s);
    bn_kernel<<<1, 512, 0, stream>>>(s, gamma, beta, sn);
    mlp_fused<<<B_, 512, 0, stream>>>(sn, W3, b3, W4, b4, out);
}

// Round 13
// 488.553 us; speedup vs baseline: 1.1707x; 1.1707x over previous
//
#include <hip/hip_runtime.h>
#include <cstdint>
#include <cstddef>

#define B_  64
#define O_  36
#define D_  512
#define P_  (O_*O_)     // 1296 pairs per batch
#define BO_ (B_*O_)     // 2304 object rows

typedef short s8v __attribute__((ext_vector_type(8)));   // 8 bf16 (4 VGPRs)
typedef float f4v __attribute__((ext_vector_type(4)));   // MFMA accumulator

// RNE float->bf16 split: x ~= hi + lo with ~16 mantissa bits total.
__device__ __forceinline__ void bsplit(float x, short& hi, short& lo) {
    unsigned u = __float_as_uint(x);
    unsigned r = (u + 0x7FFFu + ((u >> 16) & 1u)) >> 16;
    hi = (short)r;
    float hf = __uint_as_float(r << 16);
    float d = x - hf;
    unsigned u2 = __float_as_uint(d);
    unsigned r2 = (u2 + 0x7FFFu + ((u2 >> 16) & 1u)) >> 16;
    lo = (short)r2;
}

// ---------------------------------------------------------------------------
// Kernel 0: split W2 ([512][512]) and repack+split W1 ([512][1024]->[1024][512])
// into bf16 hi/lo; also zeroes the s accumulator (replaces memset launch).
// ---------------------------------------------------------------------------
__global__ __launch_bounds__(256) void wsplit_all(
    const float* __restrict__ W2, const float* __restrict__ W1,
    short* __restrict__ W2h, short* __restrict__ W2l,
    short* __restrict__ W1h, short* __restrict__ W1l,
    float* __restrict__ s)
{
    const int gt = blockIdx.x * 256 + threadIdx.x;
    if (gt < 8192)   // zero s: 8192 * float4 = 64*512 floats
        *(float4*)&s[gt * 4] = make_float4(0.f, 0.f, 0.f, 0.f);
    int i = gt * 4;
    float4 w;
    short* hip_; short* lop_; int o;
    if (i < 512 * 512) {
        w = *(const float4*)&W2[i];
        hip_ = W2h; lop_ = W2l; o = i;
    } else {
        o = i - 512 * 512;
        const int n = o >> 9, d = o & 511;
        w = *(const float4*)&W1[(size_t)(n & 511) * 1024 + ((n >> 9) << 9) + d];
        hip_ = W1h; lop_ = W1l;
    }
    short h0, l0, h1, l1, h2, l2, h3, l3;
    bsplit(w.x, h0, l0); bsplit(w.y, h1, l1);
    bsplit(w.z, h2, l2); bsplit(w.w, h3, l3);
    *(short4*)&hip_[o] = make_short4(h0, h1, h2, h3);
    *(short4*)&lop_[o] = make_short4(l0, l1, l2, l3);
}

// ---------------------------------------------------------------------------
// Kernel 1: U/V GEMM via split-bf16 MFMA (validated rounds 3/5/8/12, unchanged).
// ---------------------------------------------------------------------------
__global__ __launch_bounds__(256, 2) void uv_mfma(
    const float* __restrict__ objs,
    const short* __restrict__ W1h, const short* __restrict__ W1l,
    float* __restrict__ U, float* __restrict__ V)
{
    __shared__ short Ah[128 * 40];
    __shared__ short Al[128 * 40];
    __shared__ short Bh[128 * 40];
    __shared__ short Bl[128 * 40];

    const int tid  = threadIdx.x;
    const int lane = tid & 63;
    const int wid  = tid >> 6;
    const int wr   = wid >> 1, wc = wid & 1;
    const int rowbase = blockIdx.y * 128;   // 18 tiles over 2304
    const int colbase = blockIdx.x * 128;   // 8 tiles over 1024

    const int srow = tid >> 1;
    const int skq  = (tid & 1) * 8;
    const float* Xrow  = objs + (size_t)(rowbase + srow) * 512;
    const short* Whrow = W1h + (size_t)(colbase + srow) * 512;
    const short* Wlrow = W1l + (size_t)(colbase + srow) * 512;

    const int fr = lane & 15;
    const int sl = (lane >> 4) * 8;
    const int abase = (wr * 64 + fr) * 40 + sl;
    const int bbase = (wc * 64 + fr) * 40 + sl;

    f4v acc[4][4];
    const f4v zero = {0.f, 0.f, 0.f, 0.f};
    #pragma unroll
    for (int i = 0; i < 4; ++i)
        #pragma unroll
        for (int j = 0; j < 4; ++j) acc[i][j] = zero;

    for (int kt = 0; kt < 512; kt += 32) {
        __syncthreads();
        #pragma unroll
        for (int pass = 0; pass < 2; ++pass) {
            const int kq = skq + pass * 16;   // 0/8/16/24
            const float4 x0 = *(const float4*)&Xrow[kt + kq];
            const float4 x1 = *(const float4*)&Xrow[kt + kq + 4];
            float hx[8] = {x0.x, x0.y, x0.z, x0.w, x1.x, x1.y, x1.z, x1.w};
            s8v hi8, lo8;
            #pragma unroll
            for (int j = 0; j < 8; ++j) { short h, l; bsplit(hx[j], h, l); hi8[j] = h; lo8[j] = l; }
            *(s8v*)&Ah[srow * 40 + kq] = hi8;
            *(s8v*)&Al[srow * 40 + kq] = lo8;
            *(s8v*)&Bh[srow * 40 + kq] = *(const s8v*)&Whrow[kt + kq];
            *(s8v*)&Bl[srow * 40 + kq] = *(const s8v*)&Wlrow[kt + kq];
        }
        __syncthreads();

        s8v ah[4], al[4], bh[4], bl[4];
        #pragma unroll
        for (int f = 0; f < 4; ++f) {
            ah[f] = *(const s8v*)&Ah[abase + f * 640];
            al[f] = *(const s8v*)&Al[abase + f * 640];
            bh[f] = *(const s8v*)&Bh[bbase + f * 640];
            bl[f] = *(const s8v*)&Bl[bbase + f * 640];
        }
        #pragma unroll
        for (int fm = 0; fm < 4; ++fm)
            #pragma unroll
            for (int fn = 0; fn < 4; ++fn)
                acc[fm][fn] = __builtin_amdgcn_mfma_f32_16x16x32_bf16(ah[fm], bh[fn], acc[fm][fn], 0, 0, 0);
        #pragma unroll
        for (int fm = 0; fm < 4; ++fm)
            #pragma unroll
            for (int fn = 0; fn < 4; ++fn)
                acc[fm][fn] = __builtin_amdgcn_mfma_f32_16x16x32_bf16(ah[fm], bl[fn], acc[fm][fn], 0, 0, 0);
        #pragma unroll
        for (int fm = 0; fm < 4; ++fm)
            #pragma unroll
            for (int fn = 0; fn < 4; ++fn)
                acc[fm][fn] = __builtin_amdgcn_mfma_f32_16x16x32_bf16(al[fm], bh[fn], acc[fm][fn], 0, 0, 0);
    }

    float* dst = (colbase < 512) ? U : V;
    const int cb = colbase & 511;
    const int r4 = (lane >> 4) * 4;
    #pragma unroll
    for (int fm = 0; fm < 4; ++fm) {
        #pragma unroll
        for (int r = 0; r < 4; ++r) {
            const int row = rowbase + wr * 64 + fm * 16 + r4 + r;
            float* drow = &dst[(size_t)row * 512 + cb + wc * 64 + fr];
            #pragma unroll
            for (int fn = 0; fn < 4; ++fn) drow[fn * 16] = acc[fm][fn][r];
        }
    }
}

// ---------------------------------------------------------------------------
// Kernel 2: pair GEMM. r3-structure (2 barriers/K-step, 128x128, 4 waves,
// single LDS tile set) + raw-prefetch: next step's U/V rows and W2 tile are
// loaded global->reg at the START of the MFMA region, so the only barrier
// that drains them sits AFTER ~48 MFMAs (~470 cyc) — latency hidden. The
// stage phase is pure VALU + ds_write. Conflict-free [oct][row][8] layout
// (r8: 0 conflicts). MFMA grouping = r3's (fastest measured); per-acc order
// hh->hl->lh (numerics identical to r3/r8/r12, absmax 0.00390625).
// ---------------------------------------------------------------------------
__global__ __launch_bounds__(256, 2) void pair_gemm(
    const float* __restrict__ U, const float* __restrict__ V,
    const float* __restrict__ b1,
    const short* __restrict__ W2h, const short* __restrict__ W2l,
    const float* __restrict__ b2,
    float* __restrict__ xout, float* __restrict__ s)
{
    __shared__ short Ah[4][128][8];   // [k-octet][pair row][8 k]
    __shared__ short Al[4][128][8];
    __shared__ short Bh[4][128][8];   // [k-octet][out col][8 k]
    __shared__ short Bl[4][128][8];
    __shared__ float b1s[512];

    const int tid  = threadIdx.x;
    const int lane = tid & 63;
    const int wid  = tid >> 6;          // 0..3
    const int wr   = wid >> 1, wc = wid & 1;
    const int b       = blockIdx.z;
    const int pbase   = blockIdx.y * 128;    // 11 tiles over 1296
    const int colbase = blockIdx.x * 128;    // 4 tiles over 512

    for (int g = tid; g < 512; g += 256) b1s[g] = b1[g];

    // A staging role: thread covers row (tid&127), octets {a0, a0+1}
    const int arow = tid & 127;
    const int a0   = (tid >> 7) * 2;         // 0 or 2
    const int p    = pbase + arow;
    const bool valid = (p < P_);
    int ki = 0, mi = 0;
    if (valid) { ki = p / O_; mi = p - ki * O_; }
    const float* Urow = U + (size_t)(b * O_ + mi) * 512 + a0 * 8;
    const float* Vrow = V + (size_t)(b * O_ + ki) * 512 + a0 * 8;

    // B staging role: thread (oct=wid, row=lane) covers rows lane, lane+64
    const short* Wh0 = W2h + (size_t)(colbase + lane) * 512 + wid * 8;
    const short* Wh1 = Wh0 + (size_t)64 * 512;
    const short* Wl0 = W2l + (size_t)(colbase + lane) * 512 + wid * 8;
    const short* Wl1 = Wl0 + (size_t)64 * 512;

    const int fr = lane & 15;           // frag row (A) / col (B)
    const int q  = lane >> 4;           // k-octet 0..3

    // raw prefetch registers (next K-step)
    float4 ru0[2], ru1[2], rv0[2], rv1[2];   // A: 2 octets x (U lo4,hi4 / V lo4,hi4)
    s8v rbh0, rbh1, rbl0, rbl1;              // B: rows lane, lane+64 (hi/lo)

#define LOAD_RAW(ktv) do { const int _k = (ktv); \
    if (valid) { \
        _Pragma("unroll") for (int _j = 0; _j < 2; ++_j) { \
            ru0[_j] = *(const float4*)&Urow[_k + _j * 8]; \
            ru1[_j] = *(const float4*)&Urow[_k + _j * 8 + 4]; \
            rv0[_j] = *(const float4*)&Vrow[_k + _j * 8]; \
            rv1[_j] = *(const float4*)&Vrow[_k + _j * 8 + 4]; } } \
    rbh0 = *(const s8v*)&Wh0[_k]; rbh1 = *(const s8v*)&Wh1[_k]; \
    rbl0 = *(const s8v*)&Wl0[_k]; rbl1 = *(const s8v*)&Wl1[_k]; } while (0)

#define STAGE(ktv) do { const int _k = (ktv); \
    _Pragma("unroll") for (int _j = 0; _j < 2; ++_j) { \
        const int _oct = a0 + _j; \
        s8v _hi, _lo; \
        if (valid) { \
            const float4 _c0 = *(const float4*)&b1s[_k + _oct * 8]; \
            const float4 _c1 = *(const float4*)&b1s[_k + _oct * 8 + 4]; \
            float _hx[8]; \
            _hx[0] = fmaxf(ru0[_j].x + rv0[_j].x + _c0.x, 0.f); \
            _hx[1] = fmaxf(ru0[_j].y + rv0[_j].y + _c0.y, 0.f); \
            _hx[2] = fmaxf(ru0[_j].z + rv0[_j].z + _c0.z, 0.f); \
            _hx[3] = fmaxf(ru0[_j].w + rv0[_j].w + _c0.w, 0.f); \
            _hx[4] = fmaxf(ru1[_j].x + rv1[_j].x + _c1.x, 0.f); \
            _hx[5] = fmaxf(ru1[_j].y + rv1[_j].y + _c1.y, 0.f); \
            _hx[6] = fmaxf(ru1[_j].z + rv1[_j].z + _c1.z, 0.f); \
            _hx[7] = fmaxf(ru1[_j].w + rv1[_j].w + _c1.w, 0.f); \
            _Pragma("unroll") for (int _e = 0; _e < 8; ++_e) { short _h, _l; bsplit(_hx[_e], _h, _l); _hi[_e] = _h; _lo[_e] = _l; } \
        } else { \
            _Pragma("unroll") for (int _e = 0; _e < 8; ++_e) { _hi[_e] = 0; _lo[_e] = 0; } \
        } \
        *(s8v*)&Ah[_oct][arow][0] = _hi; \
        *(s8v*)&Al[_oct][arow][0] = _lo; } \
    *(s8v*)&Bh[wid][lane][0]      = rbh0; \
    *(s8v*)&Bh[wid][64 + lane][0] = rbh1; \
    *(s8v*)&Bl[wid][lane][0]      = rbl0; \
    *(s8v*)&Bl[wid][64 + lane][0] = rbl1; } while (0)

    f4v acc[4][4];
    const f4v zero = {0.f, 0.f, 0.f, 0.f};
    #pragma unroll
    for (int i = 0; i < 4; ++i)
        #pragma unroll
        for (int j = 0; j < 4; ++j) acc[i][j] = zero;

    LOAD_RAW(0);
    __syncthreads();                 // b1s ready
    for (int kt = 0; kt < 512; kt += 32) {
        STAGE(kt);                   // pure VALU + ds_write (raw already in regs)
        __syncthreads();             // tile ready (drains lgkm only)
        s8v ah[4], al[4], bh[4], bl[4];
        #pragma unroll
        for (int f = 0; f < 4; ++f) {
            ah[f] = *(const s8v*)&Ah[q][wr * 64 + f * 16 + fr][0];
            al[f] = *(const s8v*)&Al[q][wr * 64 + f * 16 + fr][0];
            bh[f] = *(const s8v*)&Bh[q][wc * 64 + f * 16 + fr][0];
            bl[f] = *(const s8v*)&Bl[q][wc * 64 + f * 16 + fr][0];
        }
        if (kt < 480) LOAD_RAW(kt + 32);   // issued at MFMA start -> drains at
                                           // end-of-iter barrier, hidden by MFMA
        #pragma unroll
        for (int fm = 0; fm < 4; ++fm)
            #pragma unroll
            for (int fn = 0; fn < 4; ++fn) {
                acc[fm][fn] = __builtin_amdgcn_mfma_f32_16x16x32_bf16(ah[fm], bh[fn], acc[fm][fn], 0, 0, 0);
                acc[fm][fn] = __builtin_amdgcn_mfma_f32_16x16x32_bf16(ah[fm], bl[fn], acc[fm][fn], 0, 0, 0);
                acc[fm][fn] = __builtin_amdgcn_mfma_f32_16x16x32_bf16(al[fm], bh[fn], acc[fm][fn], 0, 0, 0);
            }
        __syncthreads();             // LDS free for next STAGE; raw loads drained
    }

    // ---- epilogue: bias+relu, store x_pairs, column sums (validated r3/r8)
    float b2v[4];
    #pragma unroll
    for (int fn = 0; fn < 4; ++fn) b2v[fn] = b2[colbase + wc * 64 + fn * 16 + fr];
    const int r4 = (lane >> 4) * 4;
    float csum[4] = {0.f, 0.f, 0.f, 0.f};
    #pragma unroll
    for (int fm = 0; fm < 4; ++fm) {
        const int prow0 = pbase + wr * 64 + fm * 16 + r4;
        #pragma unroll
        for (int r = 0; r < 4; ++r) {
            const int pp = prow0 + r;
            if (pp < P_) {
                float* xrow = &xout[(size_t)(b * P_ + pp) * 512 + colbase + wc * 64 + fr];
                #pragma unroll
                for (int fn = 0; fn < 4; ++fn) {
                    float x = fmaxf(acc[fm][fn][r] + b2v[fn], 0.f);
                    xrow[fn * 16] = x;
                    csum[fn] += x;
                }
            }
        }
    }
    #pragma unroll
    for (int fn = 0; fn < 4; ++fn) {
        csum[fn] += __shfl_xor(csum[fn], 16);
        csum[fn] += __shfl_xor(csum[fn], 32);
    }
    if (lane < 16) {
        #pragma unroll
        for (int fn = 0; fn < 4; ++fn)
            atomicAdd(&s[b * 512 + colbase + wc * 64 + fn * 16 + lane], csum[fn]);
    }
#undef LOAD_RAW
#undef STAGE
}

// ---------------------------------------------------------------------------
// Kernel 3: BatchNorm over batch axis (batch stats, biased var).
// ---------------------------------------------------------------------------
__global__ __launch_bounds__(512) void bn_kernel(
    const float* __restrict__ s, const float* __restrict__ gamma,
    const float* __restrict__ beta, float* __restrict__ sn)
{
    const int g = threadIdx.x;
    float v[64];
    #pragma unroll
    for (int b = 0; b < 64; ++b) v[b] = s[b * 512 + g];
    float mean = 0.f;
    #pragma unroll
    for (int b = 0; b < 64; ++b) mean += v[b];
    mean *= (1.f / B_);
    float var = 0.f;
    #pragma unroll
    for (int b = 0; b < 64; ++b) { const float d = v[b] - mean; var = fmaf(d, d, var); }
    var *= (1.f / B_);
    const float inv = 1.f / sqrtf(var + 1e-5f);
    const float ga = gamma[g], be = beta[g];
    #pragma unroll
    for (int b = 0; b < 64; ++b)
        sn[b * 512 + g] = (v[b] - mean) * inv * ga + be;
}

// ---------------------------------------------------------------------------
// Kernel 4: fused 2-layer MLP. One block per batch row, 512 threads.
// ---------------------------------------------------------------------------
__global__ __launch_bounds__(512) void mlp_fused(
    const float* __restrict__ sn,
    const float* __restrict__ W3, const float* __restrict__ b3,
    const float* __restrict__ W4, const float* __restrict__ b4,
    float* __restrict__ out)
{
    __shared__ float xs[512];
    __shared__ float as_[512];
    const int b = blockIdx.x;
    const int f = threadIdx.x;
    xs[f] = sn[b * 512 + f];
    __syncthreads();
    float sum = 0.f;
    #pragma unroll 8
    for (int k = 0; k < 512; k += 4) {
        const float4 w4 = *(const float4*)&W3[(size_t)f * 512 + k];
        const float4 x4 = *(const float4*)&xs[k];
        sum = fmaf(w4.x, x4.x, sum); sum = fmaf(w4.y, x4.y, sum);
        sum = fmaf(w4.z, x4.z, sum); sum = fmaf(w4.w, x4.w, sum);
    }
    as_[f] = fmaxf(sum + b3[f], 0.f);
    __syncthreads();
    float sum2 = 0.f;
    #pragma unroll 8
    for (int k = 0; k < 512; k += 4) {
        const float4 w4 = *(const float4*)&W4[(size_t)f * 512 + k];
        const float4 x4 = *(const float4*)&as_[k];
        sum2 = fmaf(w4.x, x4.x, sum2); sum2 = fmaf(w4.y, x4.y, sum2);
        sum2 = fmaf(w4.z, x4.z, sum2); sum2 = fmaf(w4.w, x4.w, sum2);
    }
    out[b * 512 + f] = fmaxf(sum2 + b4[f], 0.f);
}

// ---------------------------------------------------------------------------
extern "C" void kernel_launch(void* const* d_in, const int* in_sizes, int n_in,
                              void* d_out, int out_size, void* d_ws, size_t ws_size,
                              hipStream_t stream)
{
    const float* objs  = (const float*)d_in[0];
    const float* W1    = (const float*)d_in[1];
    const float* b1    = (const float*)d_in[2];
    const float* W2    = (const float*)d_in[3];
    const float* b2    = (const float*)d_in[4];
    const float* gamma = (const float*)d_in[5];
    const float* beta  = (const float*)d_in[6];
    const float* W3    = (const float*)d_in[7];
    const float* b3    = (const float*)d_in[8];
    const float* W4    = (const float*)d_in[9];
    const float* b4    = (const float*)d_in[10];

    float* out  = (float*)d_out;           // agg: [64][512] first
    float* xout = out + B_ * 512;          // x_pairs: [64][1296][512]

    // workspace (floats then bf16): U, V, s, sn, W2h/l, W1h/l (~13 MB)
    float* U  = (float*)d_ws;
    float* V  = U  + (size_t)BO_ * 512;
    float* s  = V  + (size_t)BO_ * 512;
    float* sn = s  + B_ * 512;
    short* W2h = (short*)(sn + B_ * 512);
    short* W2l = W2h + (size_t)512 * 512;
    short* W1h = W2l + (size_t)512 * 512;
    short* W1l = W1h + (size_t)1024 * 512;

    wsplit_all<<<768, 256, 0, stream>>>(W2, W1, W2h, W2l, W1h, W1l, s);
    uv_mfma<<<dim3(8, 18), 256, 0, stream>>>(objs, W1h, W1l, U, V);
    pair_gemm<<<dim3(4, 11, B_), 256, 0, stream>>>(U, V, b1, W2h, W2l, b2, xout, s);
    bn_kernel<<<1, 512, 0, stream>>>(s, gamma, beta, sn);
    mlp_fused<<<B_, 512, 0, stream>>>(sn, W3, b3, W4, b4, out);
}